// Round 3
// baseline (15006.575 us; speedup 1.0000x reference)
//
#include <hip/hip_runtime.h>
#include <math.h>

#define NB   256   // one block per CU — co-resident (132 KB LDS forces 1/CU)
#define NT   512
#define Bsz  256
#define Ssz  256
#define Hsz  512
#define Osz  512
#define RSTRIDE 1032   // LDS row stride in floats (1024 + 8 pad: spreads bank quads)

#define AGENT __HIP_MEMORY_SCOPE_AGENT
#define RLX   __ATOMIC_RELAXED

// Dynamic LDS: 32 rows x RSTRIDE floats (132 KB). Within a row, the 1024-float
// x-vector [emb(x_t) | h] is stored slot-transposed at float4 granularity:
// group g = k>>2 lives at slot (g&15)*16 + (g>>4), i.e. float-idx
// (slot<<2)|(k&3). GEMM reader thread ks then reads 16B at base ks*4 with
// compile-time offsets i*256B; the 16 ks-lanes cover one contiguous 256B run
// (2 bank rows, 2-way = free). emb occupies slot%16 in 0..7 (byte offset +0),
// h in 8..15 (float offset +32 within each 64-float slot quad).
extern __shared__ float sx[];

__device__ __forceinline__ int ldsT_h(int r, int c) {
  // float-idx of h element c (global k = 512+c) in row r
  return r * RSTRIDE + (((c >> 2) & 15) << 6) + 32 + ((c >> 6) << 2) + (c & 3);
}

// Stage the h-half of all 32 rows from global buffer src (agent-scope loads
// bypass L1/L2 -> no stale data). BATCHED: issue all 16 LLC loads first so
// they overlap. h-half lives at +32 floats within each 64-float slot quad.
__device__ __forceinline__ void stage_h(const float* src, int b0, int tid) {
  const int r = tid >> 4, l = tid & 15;
  const float* rowp = src + (((size_t)(b0 + r)) << 9);
  unsigned long long v0[8], v1[8];
  #pragma unroll
  for (int m = 0; m < 8; ++m) {
    const int kk = (m + l) & 7;
    const int c0 = (kk << 6) + (l << 2);          // float4-aligned c
    v0[m] = __hip_atomic_load((const unsigned long long*)(rowp + c0), RLX, AGENT);
    v1[m] = __hip_atomic_load((const unsigned long long*)(rowp + c0 + 2), RLX, AGENT);
  }
  #pragma unroll
  for (int m = 0; m < 8; ++m) {
    const int kk = (m + l) & 7;
    float* d = &sx[r * RSTRIDE + (l << 6) + 32 + (kk << 2)];   // +32: h slots
    *(unsigned long long*)d       = v0[m];
    *(unsigned long long*)(d + 2) = v1[m];
  }
}

// Per-batch-group barrier: the 8 bgrps are fully independent recurrences
// (RH/H/LDS dataflow never crosses a bgrp), so sync only the 32 partner
// blocks. Release: every wave drains its outstanding stores (s_waitcnt 0)
// BEFORE __syncthreads, so all agent-scope stores are LLC-visible before the
// flag store.
__device__ __forceinline__ void group_barrier(unsigned* flags, unsigned& target,
                                              int gbase, int tid, int bid) {
  ++target;
  __builtin_amdgcn_s_waitcnt(0);      // drain this wave's vm/lgkm (release)
  __syncthreads();
  __atomic_signal_fence(__ATOMIC_SEQ_CST);
  if (tid == 0)
    __hip_atomic_store(&flags[bid], target, RLX, AGENT);
  if (tid < 32) {
    while (__hip_atomic_load(&flags[gbase + tid], RLX, AGENT) < target)
      __builtin_amdgcn_s_sleep(2);
  }
  __atomic_signal_fence(__ATOMIC_SEQ_CST);
  __syncthreads();
}

// __launch_bounds__(NT, 1): LDS (132 KB) already caps us at 1 block/CU =
// 8 waves = 2 waves/SIMD, so allow the full 256-VGPR budget. With (NT, 2)
// the compiler capped VGPRs at 128 — but wa4+wb4 alone are 128 floats, so
// the round-2 xv prefetch spilled to scratch (+4.1 GB WRITE_SIZE, measured).
__global__ __launch_bounds__(NT, 1) void gru_persistent(
    const int* __restrict__ x, const float* __restrict__ emb,
    const float* __restrict__ Wg, const float* __restrict__ bgp,
    const float* __restrict__ Wh, const float* __restrict__ bhp,
    const float* __restrict__ Wo, const float* __restrict__ bop,
    float* __restrict__ out, float* __restrict__ ws)
{
  const int tid  = threadIdx.x;
  const int bid  = blockIdx.x;
  const int bgrp = bid >> 5;          // 8 row-groups of 32 batch rows
  const int jg   = bid & 31;          // 32 column-slice groups
  const int gbase = bgrp << 5;        // first bid of this group's 32 partners
  const int b0   = bgrp << 5;
  const int j    = tid >> 4;          // output col within slice (0..31)
  const int ks   = tid & 15;          // K-slice (64 floats)
  const bool is_cand = (jg < 16);
  const int j0a = jg << 5;            // phase-A gate col base (0..1023)
  const int j0b = (jg & 15) << 5;     // phase-B col base (0..511)

  unsigned* flags = (unsigned*)ws;    // [256] barrier flags (memset 0)
  float* H0 = ws + 256;               // [256][512] h ping (memset 0 = h0)
  float* H1 = H0 + Bsz * Hsz;
  float* RH = H1 + Bsz * Hsz;
  float* ys = out + Bsz * Hsz;

  __shared__ float szv[32][32];
  __shared__ float shv[32][32];
  __shared__ int   sIdxN[32];         // next step's token index per row

  // ---- persistent register weights ----
  float4 wa4[16];
  {
    const float4* p = (const float4*)(Wg + (size_t)(j0a + j) * 1024 + (ks << 6));
    #pragma unroll
    for (int i = 0; i < 16; ++i) wa4[i] = p[i];
  }
  float4 wb4[16];
  if (is_cand) {
    const float4* p = (const float4*)(Wh + (size_t)(j0b + j) * 1024 + (ks << 6));
    #pragma unroll
    for (int i = 0; i < 16; ++i) wb4[i] = p[i];
  } else {
    const float4* p = (const float4*)(Wo + (size_t)(j0b + j) * 512 + (ks << 5));
    #pragma unroll
    for (int i = 0; i < 8; ++i) wb4[i] = p[i];
    #pragma unroll
    for (int i = 8; i < 16; ++i) wb4[i] = make_float4(0.f, 0.f, 0.f, 0.f);
  }
  const float bA = bgp[j0a + j];
  const float bB = is_cand ? bhp[j0b + j] : bop[j0b + j];

  // ---- xe prefetch state: thread (pr,pl) owns 8 float4 of row pr's emb ----
  const int pr = tid >> 4, pl = tid & 15;
  float4 xv[8];

  // pre-loop: token indices for t=0, then issue the emb gather into regs
  if (tid < 32) sIdxN[tid] = x[(b0 + tid) * Ssz];
  __syncthreads();
  {
    const float4* ep = (const float4*)(emb + (size_t)sIdxN[pr] * Hsz);
    #pragma unroll
    for (int m = 0; m < 8; ++m) xv[m] = ep[(((m + pl) & 7) << 4) + pl];
  }

  unsigned target = 0;

  for (int t = 0; t < Ssz; ++t) {
    float* Hc = (t & 1) ? H1 : H0;
    float* Hn = (t & 1) ? H0 : H1;

    // ---- commit prefetched emb half to LDS (lane-rotated kk: bank spread) ----
    #pragma unroll
    for (int m = 0; m < 8; ++m) {
      const int kk = (m + pl) & 7;
      *(float4*)&sx[pr * RSTRIDE + (pl << 6) + (kk << 2)] = xv[m];
    }
    // ---- stage h half via LLC ----
    stage_h(Hc, b0, tid);
    __syncthreads();

    // issue next step's token indices early (consumed at the mid barrier)
    if (tid < 32)
      sIdxN[tid] = x[(b0 + tid) * Ssz + ((t + 1 < Ssz) ? t + 1 : t)];

    // ---------------- Phase A: gates ----------------
    {
      const int bx = (ks << 2);
      #pragma unroll 2
      for (int r = 0; r < 32; ++r) {
        const float* xp = &sx[r * RSTRIDE + bx];
        float a0 = 0.f, a1 = 0.f, a2 = 0.f, a3 = 0.f;
        #pragma unroll
        for (int i = 0; i < 16; ++i) {
          const float4 xvv = *(const float4*)(xp + (i << 6));
          a0 += wa4[i].x * xvv.x; a1 += wa4[i].y * xvv.y;
          a2 += wa4[i].z * xvv.z; a3 += wa4[i].w * xvv.w;
        }
        float acc = (a0 + a1) + (a2 + a3);
        acc += __shfl_xor(acc, 1);
        acc += __shfl_xor(acc, 2);
        acc += __shfl_xor(acc, 4);
        acc += __shfl_xor(acc, 8);
        if (ks == 0) {
          const float s = 1.f / (1.f + expf(-(acc + bA)));
          if (is_cand) {
            szv[r][j] = s;
            shv[r][j] = sx[ldsT_h(r, j0b + j)];
          } else {
            const int hj = j0a + j - 512;
            const float hv = sx[ldsT_h(r, hj)];
            __hip_atomic_store(RH + (((size_t)(b0 + r)) << 9) + hj, s * hv, RLX, AGENT);
          }
        }
      }
    }

    // ---------------- mid barrier (per-bgrp) with xe-prefetch in the window ----
    {
      ++target;
      __builtin_amdgcn_s_waitcnt(0);
      __syncthreads();                 // sIdxN now visible to all waves
      __atomic_signal_fence(__ATOMIC_SEQ_CST);
      if (tid == 0)
        __hip_atomic_store(&flags[bid], target, RLX, AGENT);
      // issue t+1's emb gather while the group converges; latency hides
      // under the poll + all of phase B
      {
        const float4* ep = (const float4*)(emb + (size_t)sIdxN[pr] * Hsz);
        #pragma unroll
        for (int m = 0; m < 8; ++m) xv[m] = ep[(((m + pl) & 7) << 4) + pl];
      }
      if (tid < 32) {
        while (__hip_atomic_load(&flags[gbase + tid], RLX, AGENT) < target)
          __builtin_amdgcn_s_sleep(2);
      }
      __atomic_signal_fence(__ATOMIC_SEQ_CST);
      __syncthreads();
    }

    // ---------------- Phase B ----------------
    if (is_cand) {
      stage_h(RH, b0, tid);     // overwrite h-half with r*h
      __syncthreads();
      const int bx = (ks << 2);
      #pragma unroll 2
      for (int r = 0; r < 32; ++r) {
        const float* xp = &sx[r * RSTRIDE + bx];
        float a0 = 0.f, a1 = 0.f, a2 = 0.f, a3 = 0.f;
        #pragma unroll
        for (int i = 0; i < 16; ++i) {
          const float4 xvv = *(const float4*)(xp + (i << 6));
          a0 += wb4[i].x * xvv.x; a1 += wb4[i].y * xvv.y;
          a2 += wb4[i].z * xvv.z; a3 += wb4[i].w * xvv.w;
        }
        float acc = (a0 + a1) + (a2 + a3);
        acc += __shfl_xor(acc, 1);
        acc += __shfl_xor(acc, 2);
        acc += __shfl_xor(acc, 4);
        acc += __shfl_xor(acc, 8);
        if (ks == 0) {
          const float cd = tanhf(acc + bB);
          const float zv = szv[r][j], hv = shv[r][j];
          const float hn = (1.f - zv) * hv + zv * cd;
          __hip_atomic_store(Hn + (((size_t)(b0 + r)) << 9) + (j0b + j), hn, RLX, AGENT);
          if (t == Ssz - 1) out[((b0 + r) << 9) + (j0b + j)] = hn;
        }
      }
    } else if (t > 0) {
      const int by = ((ks & 1) << 9) + 32 + ((ks >> 1) << 2);
      #pragma unroll 2
      for (int r = 0; r < 32; ++r) {
        const float* xp = &sx[r * RSTRIDE + by];
        float a0 = 0.f, a1 = 0.f, a2 = 0.f, a3 = 0.f;
        #pragma unroll
        for (int i = 0; i < 8; ++i) {
          const float4 xvv = *(const float4*)(xp + (i << 6));
          a0 += wb4[i].x * xvv.x; a1 += wb4[i].y * xvv.y;
          a2 += wb4[i].z * xvv.z; a3 += wb4[i].w * xvv.w;
        }
        float acc = (a0 + a1) + (a2 + a3);
        acc += __shfl_xor(acc, 1);
        acc += __shfl_xor(acc, 2);
        acc += __shfl_xor(acc, 4);
        acc += __shfl_xor(acc, 8);
        if (ks == 0)
          ys[((size_t)(b0 + r) * Ssz + (t - 1)) * Osz + (j0b + j)] = acc + bB;
      }
    }

    group_barrier(flags, target, gbase, tid, bid);
  }

  // ---- tail: y_{S-1} from h_S (Ssz even -> h_S in H0) ----
  if (!is_cand) {
    stage_h(H0, b0, tid);
    __syncthreads();
    const int by = ((ks & 1) << 9) + 32 + ((ks >> 1) << 2);
    #pragma unroll 2
    for (int r = 0; r < 32; ++r) {
      const float* xp = &sx[r * RSTRIDE + by];
      float a0 = 0.f, a1 = 0.f, a2 = 0.f, a3 = 0.f;
      #pragma unroll
      for (int i = 0; i < 8; ++i) {
        const float4 xvv = *(const float4*)(xp + (i << 6));
        a0 += wb4[i].x * xvv.x; a1 += wb4[i].y * xvv.y;
        a2 += wb4[i].z * xvv.z; a3 += wb4[i].w * xvv.w;
      }
      float acc = (a0 + a1) + (a2 + a3);
      acc += __shfl_xor(acc, 1);
      acc += __shfl_xor(acc, 2);
      acc += __shfl_xor(acc, 4);
      acc += __shfl_xor(acc, 8);
      if (ks == 0)
        ys[((size_t)(b0 + r) * Ssz + (Ssz - 1)) * Osz + (j0b + j)] = acc + bB;
    }
  }
}

extern "C" void kernel_launch(void* const* d_in, const int* in_sizes, int n_in,
                              void* d_out, int out_size, void* d_ws, size_t ws_size,
                              hipStream_t stream) {
  const int*   x   = (const int*)  d_in[0];
  const float* emb = (const float*)d_in[1];
  const float* Wg  = (const float*)d_in[2];
  const float* bg  = (const float*)d_in[3];
  const float* Wh  = (const float*)d_in[4];
  const float* bh  = (const float*)d_in[5];
  const float* Wo  = (const float*)d_in[6];
  const float* bo  = (const float*)d_in[7];
  float* out = (float*)d_out;
  float* ws  = (float*)d_ws;

  const int dynLds = 32 * RSTRIDE * 4;   // 132,096 B
  hipFuncSetAttribute((const void*)gru_persistent,
                      hipFuncAttributeMaxDynamicSharedMemorySize, dynLds);

  // Zero barrier flags (256 u32) + H0 (= h0). ws re-poisoned every launch.
  hipMemsetAsync(d_ws, 0, (256 + Bsz * Hsz) * sizeof(float), stream);

  gru_persistent<<<NB, NT, dynLds, stream>>>(x, emb, Wg, bg, Wh, bh, Wo, bo, out, ws);
}

// Round 4
// 13783.841 us; speedup vs baseline: 1.0887x; 1.0887x over previous
//
#include <hip/hip_runtime.h>
#include <math.h>

#define NB   256   // one block per CU — co-resident (132 KB LDS forces 1/CU)
#define NT   512
#define Bsz  256
#define Ssz  256
#define Hsz  512
#define Osz  512
#define RSTRIDE 1032   // LDS row stride in floats (1024 + 8 pad: spreads bank quads)

#define AGENT __HIP_MEMORY_SCOPE_AGENT
#define RLX   __ATOMIC_RELAXED

// Dynamic LDS: 32 rows x RSTRIDE floats (132 KB). Within a row, the 1024-float
// x-vector [emb(x_t) | h] is stored slot-transposed at float4 granularity:
// group g = k>>2 lives at float-idx (g&15)*64 + (g>>4)*4 + (k&3); emb half in
// sub-offset +0, h half at +32 within each 64-float slot quad. GEMM reader
// thread ks (0..31) reads its 32-float K-slice [ks*32, ks*32+32) at base
// (ks&1)*512 + (ks>>1)*4 with compile-time offsets i*64 floats (i=0..7) —
// this single formula covers BOTH halves (the h +32 offset is absorbed).
extern __shared__ float sx[];

__device__ __forceinline__ int ldsT_h(int r, int c) {
  // float-idx of h element c (global k = 512+c) in row r
  return r * RSTRIDE + (((c >> 2) & 15) << 6) + 32 + ((c >> 6) << 2) + (c & 3);
}

// Stage the h-half of all 32 rows from global buffer src (agent-scope loads
// bypass L1/L2 -> no stale data). Batched in 2 half-rounds of 4 chunks:
// 4 outstanding LLC loads per round, only 8 ULL transient regs.
__device__ __forceinline__ void stage_h(const float* src, int b0, int tid) {
  const int r = tid >> 4, l = tid & 15;
  const float* rowp = src + (((size_t)(b0 + r)) << 9);
  #pragma unroll
  for (int hh = 0; hh < 2; ++hh) {
    unsigned long long v0[4], v1[4];
    #pragma unroll
    for (int m = 0; m < 4; ++m) {
      const int kk = ((hh << 2) + m + l) & 7;
      const int c0 = (kk << 6) + (l << 2);          // float4-aligned c
      v0[m] = __hip_atomic_load((const unsigned long long*)(rowp + c0), RLX, AGENT);
      v1[m] = __hip_atomic_load((const unsigned long long*)(rowp + c0 + 2), RLX, AGENT);
    }
    #pragma unroll
    for (int m = 0; m < 4; ++m) {
      const int kk = ((hh << 2) + m + l) & 7;
      float* d = &sx[r * RSTRIDE + (l << 6) + 32 + (kk << 2)];   // +32: h slots
      *(unsigned long long*)d       = v0[m];
      *(unsigned long long*)(d + 2) = v1[m];
    }
  }
}

// Per-batch-group barrier: the 8 bgrps are fully independent recurrences,
// so sync only the 32 partner blocks.
__device__ __forceinline__ void group_barrier(unsigned* flags, unsigned& target,
                                              int gbase, int tid, int bid) {
  ++target;
  __builtin_amdgcn_s_waitcnt(0);      // drain this wave's vm/lgkm (release)
  __syncthreads();
  __atomic_signal_fence(__ATOMIC_SEQ_CST);
  if (tid == 0)
    __hip_atomic_store(&flags[bid], target, RLX, AGENT);
  if (tid < 32) {
    while (__hip_atomic_load(&flags[gbase + tid], RLX, AGENT) < target)
      __builtin_amdgcn_s_sleep(2);
  }
  __atomic_signal_fence(__ATOMIC_SEQ_CST);
  __syncthreads();
}

// Merged 2-column butterfly reduce over 32 K-lanes: one parity select +
// shfl_xor(1) folds col0 into even lanes, col1 into odd; 4 more levels
// complete the sum. 5 shuffles for 2 columns (vs 10 naive).
__device__ __forceinline__ float reduce2(float acc0, float acc1, int ks) {
  float u = (ks & 1) ? acc1 : acc0;
  float v = (ks & 1) ? acc0 : acc1;
  u += __shfl_xor(v, 1);
  u += __shfl_xor(u, 2);
  u += __shfl_xor(u, 4);
  u += __shfl_xor(u, 8);
  u += __shfl_xor(u, 16);
  return u;   // lanes ks==0: sum(col0); ks==1: sum(col1)
}

// amdgpu_waves_per_eu(2,2): LDS (132 KB) pins 1 block/CU = 8 waves = 2/SIMD,
// so a 256-VGPR/wave budget is free. launch_bounds(NT,1) did NOT raise the
// allocator's 128-VGPR choice (measured r3: VGPR=128, 4.1 GB spill traffic);
// this attribute is the direct control.
__global__ __attribute__((amdgpu_flat_work_group_size(NT, NT),
                          amdgpu_waves_per_eu(2, 2)))
void gru_persistent(
    const int* __restrict__ x, const float* __restrict__ emb,
    const float* __restrict__ Wg, const float* __restrict__ bgp,
    const float* __restrict__ Wh, const float* __restrict__ bhp,
    const float* __restrict__ Wo, const float* __restrict__ bop,
    float* __restrict__ out, float* __restrict__ ws)
{
  const int tid  = threadIdx.x;
  const int bid  = blockIdx.x;
  const int bgrp = bid >> 5;          // 8 row-groups of 32 batch rows
  const int jg   = bid & 31;          // 32 column-slice groups
  const int gbase = bgrp << 5;
  const int b0   = bgrp << 5;
  const int jp   = tid >> 5;          // col-pair within slice (0..15)
  const int ks   = tid & 31;          // K-slice lane (32 floats each)
  const bool is_cand = (jg < 16);
  const int j0a = jg << 5;            // phase-A gate col base (0..1023)
  const int j0b = (jg & 15) << 5;     // phase-B col base (0..511)
  const int jc0 = jp << 1;            // first of this thread's 2 columns

  unsigned* flags = (unsigned*)ws;    // [256] barrier flags (memset 0)
  float* H0 = ws + 256;               // [256][512] h ping (memset 0 = h0)
  float* H1 = H0 + Bsz * Hsz;
  float* RH = H1 + Bsz * Hsz;
  float* ys = out + Bsz * Hsz;

  __shared__ float szv[32][32];
  __shared__ float shv[32][32];
  __shared__ int   sIdxN[32];         // next step's token index per row

  // ---- persistent register weights: 2 cols x 32-float K-slice per thread ----
  float4 wa0[8], wa1[8];
  {
    const float4* p0 = (const float4*)(Wg + (size_t)(j0a + jc0) * 1024 + (ks << 5));
    const float4* p1 = (const float4*)(Wg + (size_t)(j0a + jc0 + 1) * 1024 + (ks << 5));
    #pragma unroll
    for (int i = 0; i < 8; ++i) { wa0[i] = p0[i]; wa1[i] = p1[i]; }
  }
  float4 wb0[8], wb1[8];
  if (is_cand) {
    const float4* p0 = (const float4*)(Wh + (size_t)(j0b + jc0) * 1024 + (ks << 5));
    const float4* p1 = (const float4*)(Wh + (size_t)(j0b + jc0 + 1) * 1024 + (ks << 5));
    #pragma unroll
    for (int i = 0; i < 8; ++i) { wb0[i] = p0[i]; wb1[i] = p1[i]; }
  } else {
    const float4* p0 = (const float4*)(Wo + (size_t)(j0b + jc0) * 512 + (ks << 4));
    const float4* p1 = (const float4*)(Wo + (size_t)(j0b + jc0 + 1) * 512 + (ks << 4));
    #pragma unroll
    for (int i = 0; i < 4; ++i) { wb0[i] = p0[i]; wb1[i] = p1[i]; }
    #pragma unroll
    for (int i = 4; i < 8; ++i) {
      wb0[i] = make_float4(0.f, 0.f, 0.f, 0.f);
      wb1[i] = make_float4(0.f, 0.f, 0.f, 0.f);
    }
  }
  // bias for the column this thread writes in the ks<2 epilogue
  const float bA = bgp[j0a + jc0 + (ks & 1)];
  const float bB = is_cand ? bhp[j0b + jc0 + (ks & 1)] : bop[j0b + jc0 + (ks & 1)];

  // ---- xe prefetch state: thread (pr,pl) owns 8 float4 of row pr's emb ----
  const int pr = tid >> 4, pl = tid & 15;
  float4 xv[8];

  if (tid < 32) sIdxN[tid] = x[(b0 + tid) * Ssz];
  __syncthreads();
  {
    const float4* ep = (const float4*)(emb + (size_t)sIdxN[pr] * Hsz);
    #pragma unroll
    for (int m = 0; m < 8; ++m) xv[m] = ep[(((m + pl) & 7) << 4) + pl];
  }

  // GEMM reader bases (float idx): phase A/cand span full 1024-float x;
  // out-role spans the 512-float h half only.
  const int xbase = ((ks & 1) << 9) + ((ks >> 1) << 2);
  const int ybase = ((ks & 3) << 8) + 32 + ((ks >> 2) << 2);

  unsigned target = 0;

  for (int t = 0; t < Ssz; ++t) {
    float* Hc = (t & 1) ? H1 : H0;
    float* Hn = (t & 1) ? H0 : H1;

    // ---- commit prefetched emb half to LDS ----
    #pragma unroll
    for (int m = 0; m < 8; ++m) {
      const int kk = (m + pl) & 7;
      *(float4*)&sx[pr * RSTRIDE + (pl << 6) + (kk << 2)] = xv[m];
    }
    // ---- stage h half via LLC ----
    stage_h(Hc, b0, tid);
    __syncthreads();

    // issue next step's token indices early (consumed at the mid barrier)
    if (tid < 32)
      sIdxN[tid] = x[(b0 + tid) * Ssz + ((t + 1 < Ssz) ? t + 1 : t)];

    // ---------------- Phase A: gates (K=1024, 2 cols/thread) ----------------
    {
      #pragma unroll 2
      for (int r = 0; r < 32; ++r) {
        const float* xp = &sx[r * RSTRIDE + xbase];
        float p00 = 0.f, p01 = 0.f, p02 = 0.f, p03 = 0.f;
        float p10 = 0.f, p11 = 0.f, p12 = 0.f, p13 = 0.f;
        #pragma unroll
        for (int i = 0; i < 8; ++i) {
          const float4 xvv = *(const float4*)(xp + (i << 6));
          p00 += wa0[i].x * xvv.x; p01 += wa0[i].y * xvv.y;
          p02 += wa0[i].z * xvv.z; p03 += wa0[i].w * xvv.w;
          p10 += wa1[i].x * xvv.x; p11 += wa1[i].y * xvv.y;
          p12 += wa1[i].z * xvv.z; p13 += wa1[i].w * xvv.w;
        }
        const float u = reduce2((p00 + p01) + (p02 + p03),
                                (p10 + p11) + (p12 + p13), ks);
        if (ks < 2) {
          const int jj = jc0 + ks;
          const float s = 1.f / (1.f + expf(-(u + bA)));
          if (is_cand) {
            szv[r][jj] = s;
            shv[r][jj] = sx[ldsT_h(r, j0b + jj)];
          } else {
            const int hj = j0a + jj - 512;
            const float hv = sx[ldsT_h(r, hj)];
            __hip_atomic_store(RH + (((size_t)(b0 + r)) << 9) + hj, s * hv, RLX, AGENT);
          }
        }
      }
    }

    // ---------------- mid barrier (per-bgrp) with xe-prefetch in the window ----
    {
      ++target;
      __builtin_amdgcn_s_waitcnt(0);
      __syncthreads();                 // sIdxN now visible to all waves
      __atomic_signal_fence(__ATOMIC_SEQ_CST);
      if (tid == 0)
        __hip_atomic_store(&flags[bid], target, RLX, AGENT);
      {
        const float4* ep = (const float4*)(emb + (size_t)sIdxN[pr] * Hsz);
        #pragma unroll
        for (int m = 0; m < 8; ++m) xv[m] = ep[(((m + pl) & 7) << 4) + pl];
      }
      if (tid < 32) {
        while (__hip_atomic_load(&flags[gbase + tid], RLX, AGENT) < target)
          __builtin_amdgcn_s_sleep(2);
      }
      __atomic_signal_fence(__ATOMIC_SEQ_CST);
      __syncthreads();
    }

    // ---------------- Phase B ----------------
    if (is_cand) {
      stage_h(RH, b0, tid);     // overwrite h-half with r*h
      __syncthreads();
      #pragma unroll 2
      for (int r = 0; r < 32; ++r) {
        const float* xp = &sx[r * RSTRIDE + xbase];
        float p00 = 0.f, p01 = 0.f, p02 = 0.f, p03 = 0.f;
        float p10 = 0.f, p11 = 0.f, p12 = 0.f, p13 = 0.f;
        #pragma unroll
        for (int i = 0; i < 8; ++i) {
          const float4 xvv = *(const float4*)(xp + (i << 6));
          p00 += wb0[i].x * xvv.x; p01 += wb0[i].y * xvv.y;
          p02 += wb0[i].z * xvv.z; p03 += wb0[i].w * xvv.w;
          p10 += wb1[i].x * xvv.x; p11 += wb1[i].y * xvv.y;
          p12 += wb1[i].z * xvv.z; p13 += wb1[i].w * xvv.w;
        }
        const float u = reduce2((p00 + p01) + (p02 + p03),
                                (p10 + p11) + (p12 + p13), ks);
        if (ks < 2) {
          const int jj = jc0 + ks;
          const float cd = tanhf(u + bB);
          const float zv = szv[r][jj], hv = shv[r][jj];
          const float hn = (1.f - zv) * hv + zv * cd;
          __hip_atomic_store(Hn + (((size_t)(b0 + r)) << 9) + (j0b + jj), hn, RLX, AGENT);
          if (t == Ssz - 1) out[((b0 + r) << 9) + (j0b + jj)] = hn;
        }
      }
    } else if (t > 0) {
      #pragma unroll 2
      for (int r = 0; r < 32; ++r) {
        const float* xp = &sx[r * RSTRIDE + ybase];
        float p00 = 0.f, p01 = 0.f, p02 = 0.f, p03 = 0.f;
        float p10 = 0.f, p11 = 0.f, p12 = 0.f, p13 = 0.f;
        #pragma unroll
        for (int i = 0; i < 4; ++i) {
          const float4 xvv = *(const float4*)(xp + (i << 6));
          p00 += wb0[i].x * xvv.x; p01 += wb0[i].y * xvv.y;
          p02 += wb0[i].z * xvv.z; p03 += wb0[i].w * xvv.w;
          p10 += wb1[i].x * xvv.x; p11 += wb1[i].y * xvv.y;
          p12 += wb1[i].z * xvv.z; p13 += wb1[i].w * xvv.w;
        }
        const float u = reduce2((p00 + p01) + (p02 + p03),
                                (p10 + p11) + (p12 + p13), ks);
        if (ks < 2)
          ys[((size_t)(b0 + r) * Ssz + (t - 1)) * Osz + (j0b + jc0 + ks)] = u + bB;
      }
    }

    group_barrier(flags, target, gbase, tid, bid);
  }

  // ---- tail: y_{S-1} from h_S (Ssz even -> h_S in H0) ----
  if (!is_cand) {
    stage_h(H0, b0, tid);
    __syncthreads();
    #pragma unroll 2
    for (int r = 0; r < 32; ++r) {
      const float* xp = &sx[r * RSTRIDE + ybase];
      float p00 = 0.f, p01 = 0.f, p02 = 0.f, p03 = 0.f;
      float p10 = 0.f, p11 = 0.f, p12 = 0.f, p13 = 0.f;
      #pragma unroll
      for (int i = 0; i < 4; ++i) {
        const float4 xvv = *(const float4*)(xp + (i << 6));
        p00 += wb0[i].x * xvv.x; p01 += wb0[i].y * xvv.y;
        p02 += wb0[i].z * xvv.z; p03 += wb0[i].w * xvv.w;
        p10 += wb1[i].x * xvv.x; p11 += wb1[i].y * xvv.y;
        p12 += wb1[i].z * xvv.z; p13 += wb1[i].w * xvv.w;
      }
      const float u = reduce2((p00 + p01) + (p02 + p03),
                              (p10 + p11) + (p12 + p13), ks);
      if (ks < 2)
        ys[((size_t)(b0 + r) * Ssz + (Ssz - 1)) * Osz + (j0b + jc0 + ks)] = u + bB;
    }
  }
}

extern "C" void kernel_launch(void* const* d_in, const int* in_sizes, int n_in,
                              void* d_out, int out_size, void* d_ws, size_t ws_size,
                              hipStream_t stream) {
  const int*   x   = (const int*)  d_in[0];
  const float* emb = (const float*)d_in[1];
  const float* Wg  = (const float*)d_in[2];
  const float* bg  = (const float*)d_in[3];
  const float* Wh  = (const float*)d_in[4];
  const float* bh  = (const float*)d_in[5];
  const float* Wo  = (const float*)d_in[6];
  const float* bo  = (const float*)d_in[7];
  float* out = (float*)d_out;
  float* ws  = (float*)d_ws;

  const int dynLds = 32 * RSTRIDE * 4;   // 132,096 B
  hipFuncSetAttribute((const void*)gru_persistent,
                      hipFuncAttributeMaxDynamicSharedMemorySize, dynLds);

  // Zero barrier flags (256 u32) + H0 (= h0). ws re-poisoned every launch.
  hipMemsetAsync(d_ws, 0, (256 + Bsz * Hsz) * sizeof(float), stream);

  gru_persistent<<<NB, NT, dynLds, stream>>>(x, emb, Wg, bg, Wh, bh, Wo, bo, out, ws);
}